// Round 15
// baseline (158.912 us; speedup 1.0000x reference)
//
#include <hip/hip_runtime.h>

// ---- problem constants ----
#define NTOK 8192      // B*N = 8*1024
#define CDIM 768
#define HIDD 3072
#define NQKV 2304
#define SEQL 1024
#define NHEAD 12

typedef int i32x4 __attribute__((ext_vector_type(4)));
typedef float f32x4 __attribute__((ext_vector_type(4)));
typedef signed char sc16 __attribute__((ext_vector_type(16)));
typedef unsigned short us4 __attribute__((ext_vector_type(4)));

__device__ __forceinline__ unsigned short f32_to_bf16(float f) {
    unsigned int u = __float_as_uint(f);
    u += 0x7FFFu + ((u >> 16) & 1u);
    return (unsigned short)(u >> 16);
}
__device__ __forceinline__ float bf16_to_f32(unsigned short h) {
    return __uint_as_float(((unsigned)h) << 16);
}

// async global->LDS, 16B per lane. Dest must be wave-uniform base + lane*16.
__device__ __forceinline__ void gload_lds16(const void* g, void* l) {
    __builtin_amdgcn_global_load_lds(
        (const __attribute__((address_space(1))) unsigned int*)g,
        (__attribute__((address_space(3))) unsigned int*)l, 16, 0, 0);
}

// weight sign (+ optional alpha / pi-perm) helper
__device__ __forceinline__ void sign_alpha_row(
    const float* __restrict__ w, signed char* __restrict__ ws,
    float* __restrict__ alpha, int K, bool perm, int row, float* red)
{
    const float* wr = w + (size_t)row * K;
    signed char* wsr = ws + (size_t)row * K;
    float s = 0.f;
    for (int i = threadIdx.x; i < K; i += 256) {
        float v = wr[i];
        int ip = perm ? ((i & ~63) | (((i & 15) << 2) | ((i >> 4) & 3))) : i;
        wsr[ip] = (v >= 0.f) ? 1 : -1;
        s += fabsf(v);
    }
    if (alpha) {
        for (int off = 32; off > 0; off >>= 1) s += __shfl_down(s, off);
        if ((threadIdx.x & 63) == 0) red[threadIdx.x >> 6] = s;
        __syncthreads();
        if (threadIdx.x == 0) alpha[row] = (red[0] + red[1] + red[2] + red[3]) / (float)K;
    }
}

// ============================================================================
// Front-end: wqkv sign + LN1(+sign, packed u32) + bf16 copy of x (vectorized).
// Blocks: [0,2304) wqkv rows | [2304,10496) LN1 rows.
// ============================================================================
__global__ void __launch_bounds__(256) prep_front(
    const float* __restrict__ w_qkv, signed char* __restrict__ wqkv_s,
    const float* __restrict__ x, const float* __restrict__ ln1_g,
    const float* __restrict__ ln1_b, signed char* __restrict__ a1,
    unsigned short* __restrict__ xb16)
{
    const int blk = blockIdx.x;
    __shared__ float red[8];

    if (blk < 2304) {
        sign_alpha_row(w_qkv, wqkv_s, nullptr, CDIM, false, blk, red);
        return;
    }
    // ---- LN1 + sign (f32x4 loads, u32 packed stores), bf16 copy of x ----
    int row = blk - 2304;
    const int t = threadIdx.x;            // threads 0..191 active for data
    const bool act = t < 192;
    const float* xr = x + (size_t)row * CDIM;
    f32x4 xv = {0.f, 0.f, 0.f, 0.f};
    if (act) xv = *(const f32x4*)&xr[t * 4];
    if (act) {
        us4 h;
        h.x = f32_to_bf16(xv.x); h.y = f32_to_bf16(xv.y);
        h.z = f32_to_bf16(xv.z); h.w = f32_to_bf16(xv.w);
        *(us4*)&xb16[(size_t)row * CDIM + t * 4] = h;
    }
    float s = xv.x + xv.y + xv.z + xv.w;
    float s2 = xv.x * xv.x + xv.y * xv.y + xv.z * xv.z + xv.w * xv.w;
    for (int off = 32; off > 0; off >>= 1) { s += __shfl_down(s, off); s2 += __shfl_down(s2, off); }
    if ((t & 63) == 0) { red[t >> 6] = s; red[4 + (t >> 6)] = s2; }
    __syncthreads();
    float ts = red[0] + red[1] + red[2] + red[3];
    float t2 = red[4] + red[5] + red[6] + red[7];
    float mu = ts * (1.0f / CDIM);
    float var = t2 * (1.0f / CDIM) - mu * mu;
    float rstd = rsqrtf(var + 1e-5f);
    if (act) {
        f32x4 g4 = *(const f32x4*)&ln1_g[t * 4];
        f32x4 b4 = *(const f32x4*)&ln1_b[t * 4];
        unsigned pk = 0;
        float v[4] = {xv.x, xv.y, xv.z, xv.w};
        float gg[4] = {g4.x, g4.y, g4.z, g4.w};
        float bb[4] = {b4.x, b4.y, b4.z, b4.w};
#pragma unroll
        for (int e = 0; e < 4; e++) {
            float val = (v[e] - mu) * rstd * gg[e] + bb[e];
            pk |= (unsigned)(unsigned char)(signed char)((val >= 0.f) ? 1 : -1) << (8 * e);
        }
        *(unsigned*)(a1 + (size_t)row * CDIM + t * 4) = pk;
    }
}

// LayerNorm (bf16 x1, vectorized us4) -> per-row i8 quant (packed u32)
__global__ void __launch_bounds__(256) ln2q_kernel(const unsigned short* __restrict__ x, const float* __restrict__ g,
                                                   const float* __restrict__ b, signed char* __restrict__ out,
                                                   float* __restrict__ rowscale) {
    int row = blockIdx.x;
    const int t = threadIdx.x;
    const bool act = t < 192;
    float v[4] = {0.f, 0.f, 0.f, 0.f};
    if (act) {
        us4 xv = *(const us4*)&x[(size_t)row * CDIM + t * 4];
        v[0] = bf16_to_f32(xv.x); v[1] = bf16_to_f32(xv.y);
        v[2] = bf16_to_f32(xv.z); v[3] = bf16_to_f32(xv.w);
    }
    float s = v[0] + v[1] + v[2] + v[3];
    float s2 = v[0] * v[0] + v[1] * v[1] + v[2] * v[2] + v[3] * v[3];
    for (int off = 32; off > 0; off >>= 1) { s += __shfl_down(s, off); s2 += __shfl_down(s2, off); }
    __shared__ float red[8];
    __shared__ float redm[4];
    if ((t & 63) == 0) { red[t >> 6] = s; red[4 + (t >> 6)] = s2; }
    __syncthreads();
    float ts = red[0] + red[1] + red[2] + red[3];
    float t2 = red[4] + red[5] + red[6] + red[7];
    float mu = ts * (1.0f / CDIM);
    float var = t2 * (1.0f / CDIM) - mu * mu;
    float rstd = rsqrtf(var + 1e-5f);
    float a[4] = {0.f, 0.f, 0.f, 0.f};
    float mx = 0.f;
    if (act) {
        f32x4 g4 = *(const f32x4*)&g[t * 4];
        f32x4 b4 = *(const f32x4*)&b[t * 4];
        float gg[4] = {g4.x, g4.y, g4.z, g4.w};
        float bb[4] = {b4.x, b4.y, b4.z, b4.w};
#pragma unroll
        for (int e = 0; e < 4; e++) {
            a[e] = (v[e] - mu) * rstd * gg[e] + bb[e];
            mx = fmaxf(mx, fabsf(a[e]));
        }
    }
    for (int off = 32; off > 0; off >>= 1) mx = fmaxf(mx, __shfl_down(mx, off));
    if ((t & 63) == 0) redm[t >> 6] = mx;
    __syncthreads();
    float rmax = fmaxf(fmaxf(redm[0], redm[1]), fmaxf(redm[2], redm[3]));
    rmax = fmaxf(rmax, 1e-20f);
    float inv = 127.f / rmax;
    if (act) {
        unsigned pk = 0;
#pragma unroll
        for (int e = 0; e < 4; e++)
            pk |= (unsigned)(unsigned char)(signed char)__float2int_rn(a[e] * inv) << (8 * e);
        *(unsigned*)(out + (size_t)row * CDIM + t * 4) = pk;
    }
    if (t == 0) rowscale[row] = rmax * (1.f / 127.f);
}

// ---------- i8 GEMM 128x128, 4 waves (2m x 2n), 48KB LDS -> 3 blocks/CU ----------
// qkv: grid 1152 (1.5 rounds of 768 slots); fc1: grid 1536 (exactly 2.0 rounds).
enum { EPI_GELU = 2, EPI_QKV = 3 };
#define MSCALE_INV 16.0f

template<int EPI>
__global__ void __launch_bounds__(256) gemm_i8(
    const signed char* __restrict__ A, const signed char* __restrict__ B,
    int N, int K,
    const float* __restrict__ alpha, const float* __restrict__ bias,
    const float* __restrict__ rowscale,
    signed char* __restrict__ outB, signed char* __restrict__ vtB)
{
    __shared__ __align__(16) char lds_raw[3 * 256 * 64];   // 48 KB
    auto As = (signed char (*)[128][64])lds_raw;
    auto Bs = (signed char (*)[128][64])(lds_raw + 3 * 128 * 64);

    const int tid = threadIdx.x, ln = tid & 63, w = tid >> 6;
    const int wm = w >> 1, wn = w & 1;
    const int lq = ln & 15, khi = ln >> 4;

    const int nwg = gridDim.x * gridDim.y;
    const int id = blockIdx.y * gridDim.x + blockIdx.x;
    const int nid = (id & 7) * (nwg >> 3) + (id >> 3);
    const int bxs = nid % gridDim.x, bys = nid / gridDim.x;
    const int bm = bys * 128, bn = bxs * 128;

    const i32x4 iz = {0, 0, 0, 0};
    i32x4 acc[4][4];
#pragma unroll
    for (int m = 0; m < 4; m++)
#pragma unroll
        for (int n = 0; n < 4; n++) acc[m][n] = iz;

    const int srow = tid >> 2, scol = (tid & 3) * 16;
    const int ssrc = ((tid & 3) ^ ((srow >> 1) & 3)) * 16;
    const int sa = 16 * (khi ^ ((lq >> 1) & 3));

    auto STAGE = [&](int p, int k0) {
        gload_lds16(A + (size_t)(bm + srow) * K + k0 + ssrc, &As[p][srow][scol]);
        gload_lds16(A + (size_t)(bm + 64 + srow) * K + k0 + ssrc, &As[p][64 + srow][scol]);
        gload_lds16(B + (size_t)(bn + srow) * K + k0 + ssrc, &Bs[p][srow][scol]);
        gload_lds16(B + (size_t)(bn + 64 + srow) * K + k0 + ssrc, &Bs[p][64 + srow][scol]);
    };
    auto COMPUTE = [&](int p, bool prefetch, int knext) {
        i32x4 aF[4], bF[4];
#pragma unroll
        for (int m = 0; m < 4; m++) aF[m] = *(const i32x4*)&As[p][wm * 64 + m * 16 + lq][sa];
#pragma unroll
        for (int n = 0; n < 4; n++) bF[n] = *(const i32x4*)&Bs[p][wn * 64 + n * 16 + lq][sa];
        if (prefetch) STAGE((p + 2) % 3, knext);
        __builtin_amdgcn_s_setprio(1);
#pragma unroll
        for (int m = 0; m < 4; m++)
#pragma unroll
            for (int n = 0; n < 4; n++)
                acc[m][n] = __builtin_amdgcn_mfma_i32_16x16x64_i8(aF[m], bF[n], acc[m][n], 0, 0, 0);
        __builtin_amdgcn_s_setprio(0);
    };

    const int nst = K >> 6;            // 12
    STAGE(0, 0);
    STAGE(1, 64);
#pragma unroll 1
    for (int t = 0; t < nst - 1; t++) {
        asm volatile("s_waitcnt vmcnt(4)" ::: "memory");
        asm volatile("s_waitcnt lgkmcnt(0)" ::: "memory");
        __builtin_amdgcn_s_barrier();
        COMPUTE(t % 3, t + 2 < nst, (t + 2) << 6);
    }
    asm volatile("s_waitcnt vmcnt(0)" ::: "memory");
    asm volatile("s_waitcnt lgkmcnt(0)" ::: "memory");
    __builtin_amdgcn_s_barrier();
    COMPUTE((nst - 1) % 3, false, 0);

    const int r0 = bm + wm * 64;
    const int c0 = bn + wn * 64;       // wave's 64-col group

    if constexpr (EPI == EPI_GELU) {
        float al[4], bi[4];
#pragma unroll
        for (int n = 0; n < 4; n++) {
            al[n] = alpha[c0 + n * 16 + lq];
            bi[n] = bias[c0 + n * 16 + lq];
        }
#pragma unroll
        for (int m = 0; m < 4; m++)
#pragma unroll
            for (int i = 0; i < 4; i++) {
                int r = r0 + m * 16 + khi * 4 + i;
                float rs = rowscale[r];
                unsigned pk = 0;
#pragma unroll
                for (int n = 0; n < 4; n++) {
                    float t = al[n] * ((float)acc[m][n][i] * rs) + bi[n];
                    float y2 = 1.5957691f * t + 0.07135481f * t * t * t;
                    float ge = t * __builtin_amdgcn_rcpf(1.0f + __expf(-y2));
                    float qf = fminf(fmaxf(ge * MSCALE_INV, -127.f), 127.f);
                    pk |= (unsigned)(unsigned char)(signed char)__float2int_rn(qf) << (8 * n);
                }
                *(unsigned*)(outB + (size_t)r * N + c0 + lq * 4) = pk;
            }
    } else {  // EPI_QKV
        if (c0 < 1536) {
#pragma unroll
            for (int m = 0; m < 4; m++)
#pragma unroll
                for (int i = 0; i < 4; i++) {
                    int r = r0 + m * 16 + khi * 4 + i;
                    unsigned pk = 0;
#pragma unroll
                    for (int n = 0; n < 4; n++)
                        pk |= (unsigned)(unsigned char)(signed char)((acc[m][n][i] >= 0) ? 1 : -1) << (8 * n);
                    *(unsigned*)(outB + (size_t)r * 1536 + c0 + lq * 4) = pk;
                }
        } else {
#pragma unroll
            for (int m = 0; m < 4; m++)
#pragma unroll
                for (int n = 0; n < 4; n++) {
                    int cg = c0 + n * 16 + lq - 1536;
                    int hh = cg >> 6, dd = cg & 63;
                    int rb = r0 + m * 16 + khi * 4;
                    unsigned pk = 0;
#pragma unroll
                    for (int i = 0; i < 4; i++)
                        pk |= (unsigned)(unsigned char)(signed char)((acc[m][n][i] >= 0) ? 1 : -1) << (8 * i);
                    *(unsigned*)(vtB + (((size_t)(rb >> 10) * NHEAD + hh) * 64 + dd) * SEQL + (rb & 1023)) = pk;
                }
        }
    }
}

// ---------- 128x64 RESID GEMM (proj / fc2) ----------
// 3-buffer counted-vmcnt pipeline + T14 preloaded epilogue operands.
// resid is always bf16. OUTF32=false (proj): output x1 bf16; true (fc2): f32.
template<bool OUTF32>
__global__ void __launch_bounds__(256) gemm_resid(
    const signed char* __restrict__ A, const signed char* __restrict__ B,
    int N, int K,
    const float* __restrict__ alpha, const float* __restrict__ bias,
    const float* __restrict__ ls, const unsigned short* __restrict__ residH,
    float ascale,
    float* __restrict__ outF, unsigned short* __restrict__ outH)
{
    __shared__ __align__(16) char lds_raw[3 * (128 + 64) * 64];   // 36 KB; epi Cf 128x68 f32 fits
    auto As = (signed char (*)[128][64])lds_raw;
    auto Bs = (signed char (*)[64][64])(lds_raw + 3 * 128 * 64);

    const int tid = threadIdx.x, ln = tid & 63, w = tid >> 6;
    const int wm = w >> 1, wn = w & 1;
    const int lq = ln & 15, khi = ln >> 4;

    const int nwg = gridDim.x * gridDim.y;
    const int id = blockIdx.y * gridDim.x + blockIdx.x;
    const int nid = (id & 7) * (nwg >> 3) + (id >> 3);
    const int bxs = nid % gridDim.x, bys = nid / gridDim.x;
    const int bm = bys * 128, bn = bxs * 64;

    // ---- T14 preload: epilogue operands issued before any staging ----
    const int erow = tid >> 4;           // 0..15
    const int ec4 = (tid & 15) * 4;
    f32x4 a4 = *(const f32x4*)&alpha[bn + ec4];
    f32x4 b4 = *(const f32x4*)&bias[bn + ec4];
    f32x4 l4 = *(const f32x4*)&ls[bn + ec4];
    us4 rH[8];
#pragma unroll
    for (int p = 0; p < 8; p++) {
        size_t g = (size_t)(bm + p * 16 + erow) * N + bn + ec4;
        rH[p] = *(const us4*)&residH[g];
    }

    const i32x4 iz = {0, 0, 0, 0};
    i32x4 acc[4][2];
#pragma unroll
    for (int m = 0; m < 4; m++)
#pragma unroll
        for (int n = 0; n < 2; n++) acc[m][n] = iz;

    const int srow = tid >> 2, scol = (tid & 3) * 16;
    const int ssrc = ((tid & 3) ^ ((srow >> 1) & 3)) * 16;
    const int sa = 16 * (khi ^ ((lq >> 1) & 3));

    auto STAGE = [&](int p, int k0) {
        gload_lds16(A + (size_t)(bm + srow) * K + k0 + ssrc, &As[p][srow][scol]);
        gload_lds16(A + (size_t)(bm + 64 + srow) * K + k0 + ssrc, &As[p][64 + srow][scol]);
        gload_lds16(B + (size_t)(bn + srow) * K + k0 + ssrc, &Bs[p][srow][scol]);
    };
    auto COMPUTE = [&](int p, bool prefetch, int knext) {
        i32x4 aF[4], bF[2];
#pragma unroll
        for (int m = 0; m < 4; m++) aF[m] = *(const i32x4*)&As[p][wm * 64 + m * 16 + lq][sa];
#pragma unroll
        for (int n = 0; n < 2; n++) bF[n] = *(const i32x4*)&Bs[p][wn * 32 + n * 16 + lq][sa];
        if (prefetch) STAGE((p + 2) % 3, knext);
        __builtin_amdgcn_s_setprio(1);
#pragma unroll
        for (int m = 0; m < 4; m++)
#pragma unroll
            for (int n = 0; n < 2; n++)
                acc[m][n] = __builtin_amdgcn_mfma_i32_16x16x64_i8(aF[m], bF[n], acc[m][n], 0, 0, 0);
        __builtin_amdgcn_s_setprio(0);
    };

    const int nst = K >> 6;            // 12 or 48
    STAGE(0, 0);
    STAGE(1, 64);
#pragma unroll 1
    for (int t = 0; t < nst - 1; t++) {
        asm volatile("s_waitcnt vmcnt(3)" ::: "memory");   // stage t done (preloads retire first)
        asm volatile("s_waitcnt lgkmcnt(0)" ::: "memory");
        __builtin_amdgcn_s_barrier();
        COMPUTE(t % 3, t + 2 < nst, (t + 2) << 6);
    }
    asm volatile("s_waitcnt vmcnt(0)" ::: "memory");
    asm volatile("s_waitcnt lgkmcnt(0)" ::: "memory");
    __builtin_amdgcn_s_barrier();
    COMPUTE((nst - 1) % 3, false, 0);

    // ---- epilogue: LDS transpose -> pure FMA + coalesced store (resid in regs) ----
    __syncthreads();
    float (*Cf)[68] = (float (*)[68])lds_raw;
#pragma unroll
    for (int m = 0; m < 4; m++)
#pragma unroll
        for (int n = 0; n < 2; n++)
#pragma unroll
            for (int i = 0; i < 4; i++)
                Cf[wm * 64 + m * 16 + khi * 4 + i][wn * 32 + n * 16 + lq] =
                    (float)acc[m][n][i] * ascale;
    __syncthreads();
#pragma unroll
    for (int p = 0; p < 8; p++) {
        int row = p * 16 + erow;
        f32x4 v4 = *(const f32x4*)&Cf[row][ec4];
        size_t g = (size_t)(bm + row) * N + bn + ec4;
        f32x4 r;
        r.x = bf16_to_f32(rH[p].x); r.y = bf16_to_f32(rH[p].y);
        r.z = bf16_to_f32(rH[p].z); r.w = bf16_to_f32(rH[p].w);
        f32x4 o4 = r + l4 * (a4 * v4 + b4);
        if constexpr (OUTF32) {
            *(f32x4*)&outF[g] = o4;
        } else {
            us4 h;
            h.x = f32_to_bf16(o4.x); h.y = f32_to_bf16(o4.y);
            h.z = f32_to_bf16(o4.z); h.w = f32_to_bf16(o4.w);
            *(us4*)&outH[g] = h;
        }
    }
}

// ---------- binary attention (exact i8) + fused wproj/wfc1/wfc2 prep ----------
__global__ void __launch_bounds__(256) attn_prep(
    const signed char* __restrict__ qk, const signed char* __restrict__ vt,
    signed char* __restrict__ a2,
    const float* __restrict__ w_proj, const float* __restrict__ w_fc1,
    const float* __restrict__ w_fc2,
    signed char* __restrict__ wproj_s, signed char* __restrict__ wfc1_s,
    signed char* __restrict__ wfc2_s,
    float* __restrict__ a_proj, float* __restrict__ a_fc1, float* __restrict__ a_fc2)
{
    const int blk = blockIdx.x;
    if (blk >= 768) {
        __shared__ float red[4];
        if (blk < 1536)      sign_alpha_row(w_proj, wproj_s, a_proj, CDIM, true,  blk - 768, red);
        else if (blk < 4608) sign_alpha_row(w_fc1,  wfc1_s,  a_fc1,  CDIM, false, blk - 1536, red);
        else                 sign_alpha_row(w_fc2,  wfc2_s,  a_fc2,  HIDD, true,  blk - 4608, red);
        return;
    }

    const int id = blk;                              // 0..767
    const int nid = (id & 7) * 96 + (id >> 3);
    const int bh = nid >> 3, qb = nid & 7;
    const int b = bh / NHEAD, h = bh % NHEAD;
    const int tid = threadIdx.x, ln = tid & 63, w = tid >> 6;
    const int lq = ln & 15, khi = ln >> 4;

    __shared__ signed char Ks[64][80];
    __shared__ signed char Vts[64][80];
    __shared__ signed char Pw[4][32][80];

    const size_t tokbase = (size_t)b * SEQL;
    const int q0 = qb * 128 + w * 32;
    const int str = tid >> 2, stc = (tid & 3) * 16;
    const size_t vtrow = ((size_t)bh * 64 + str) * SEQL;

    i32x4 qfrag[2];
#pragma unroll
    for (int qf = 0; qf < 2; qf++)
        qfrag[qf] = *(const i32x4*)(qk + (tokbase + q0 + qf * 16 + lq) * 1536 + h * 64 + khi * 16);

    const i32x4 iz = {0, 0, 0, 0};
    i32x4 o[2][4];
#pragma unroll
    for (int qf = 0; qf < 2; qf++)
#pragma unroll
        for (int df = 0; df < 4; df++) o[qf][df] = iz;

    auto LOADJ = [&](int j, sc16& kr, sc16& vr) {
        kr = *(const sc16*)(qk + (tokbase + j * 64 + str) * 1536 + 768 + h * 64 + stc);
        vr = *(const sc16*)(vt + vtrow + j * 64 + stc);
    };
    auto STORE = [&](const sc16& kr, const sc16& vr) {
        *(sc16*)&Ks[str][stc] = kr;
        *(sc16*)&Vts[str][stc] = vr;
    };
    auto COMPUTE = [&]() {
        i32x4 kfrag[4];
#pragma unroll
        for (int kf = 0; kf < 4; kf++)
            kfrag[kf] = *(const i32x4*)&Ks[kf * 16 + lq][khi * 16];
#pragma unroll
        for (int kf = 0; kf < 4; kf++) {
#pragma unroll
            for (int qf = 0; qf < 2; qf++) {
                i32x4 st = __builtin_amdgcn_mfma_i32_16x16x64_i8(kfrag[kf], qfrag[qf], iz, 0, 0, 0);
                unsigned pb = (st[0] > 0 ? 1u : 0u) | (st[1] > 0 ? 0x100u : 0u) |
                              (st[2] > 0 ? 0x10000u : 0u) | (st[3] > 0 ? 0x1000000u : 0u);
                *(unsigned*)&Pw[w][qf * 16 + lq][kf * 16 + khi * 4] = pb;
            }
        }
        i32x4 pa[2];
#pragma unroll
        for (int qf = 0; qf < 2; qf++)
            pa[qf] = *(const i32x4*)&Pw[w][qf * 16 + lq][khi * 16];
#pragma unroll
        for (int df = 0; df < 4; df++) {
            i32x4 vfr = *(const i32x4*)&Vts[df * 16 + lq][khi * 16];
#pragma unroll
            for (int qf = 0; qf < 2; qf++)
                o[qf][df] = __builtin_amdgcn_mfma_i32_16x16x64_i8(pa[qf], vfr, o[qf][df], 0, 0, 0);
        }
    };

    sc16 ka, va, kb, vb;
    LOADJ(0, ka, va);
#pragma unroll 1
    for (int jj = 0; jj < 16; jj += 2) {
        __syncthreads();
        STORE(ka, va);
        __syncthreads();
        LOADJ(jj + 1, kb, vb);
        COMPUTE();
        __syncthreads();
        STORE(kb, vb);
        __syncthreads();
        if (jj + 2 < 16) LOADJ(jj + 2, ka, va);
        COMPUTE();
    }

    // epilogue: pi-packed u32: a2[token][h*64 + lq*4 + df] = sign(O[.][df*16+lq])
#pragma unroll
    for (int qf = 0; qf < 2; qf++)
#pragma unroll
        for (int i = 0; i < 4; i++) {
            int qrow = q0 + qf * 16 + khi * 4 + i;
            unsigned pk = 0;
#pragma unroll
            for (int df = 0; df < 4; df++)
                pk |= (unsigned)(unsigned char)(signed char)((o[qf][df][i] >= 0) ? 1 : -1) << (8 * df);
            *(unsigned*)(a2 + (tokbase + qrow) * CDIM + h * 64 + lq * 4) = pk;
        }
}

// ---------- workspace layout (bytes) ----------
static const size_t OFF_WQKV  = 0;          // 2304*768   = 1769472
static const size_t OFF_WPROJ = 1769472;    // 768*768    = 589824
static const size_t OFF_WFC1  = 2359296;    // 3072*768   = 2359296
static const size_t OFF_WFC2  = 4718592;    // 768*3072   = 2359296
static const size_t OFF_APROJ = 7077888;    // 768*4
static const size_t OFF_AFC1  = 7080960;    // 3072*4
static const size_t OFF_AFC2  = 7093248;    // 768*4
static const size_t OFF_H2SC  = 7096320;    // 8192*4
static const size_t OFF_QK    = 7129088;    // 8192*1536  = 12582912 (dead after attn)
static const size_t OFF_VT    = 19712000;   // 96*64*1024 = 6291456  (dead after attn)
static const size_t OFF_A1    = 26003456;   // 8192*768   = 6291456
static const size_t OFF_A2    = 32294912;   // 8192*768   = 6291456
static const size_t OFF_M1    = 38586368;   // 8192*3072  = 25165824
static const size_t OFF_H2    = 63752192;   // 8192*768   = 6291456
static const size_t OFF_X1B   = OFF_QK;     // bf16 x1 aliases qk
static const size_t OFF_XB16  = OFF_M1;     // bf16 x aliases m1 (dead until fc1)
// total = 70043648 bytes

extern "C" void kernel_launch(void* const* d_in, const int* in_sizes, int n_in,
                              void* d_out, int out_size, void* d_ws, size_t ws_size,
                              hipStream_t stream) {
    const float* x      = (const float*)d_in[0];
    const float* ln1_g  = (const float*)d_in[1];
    const float* ln1_b  = (const float*)d_in[2];
    const float* w_qkv  = (const float*)d_in[3];
    const float* w_proj = (const float*)d_in[4];
    const float* b_proj = (const float*)d_in[5];
    const float* ls1_g  = (const float*)d_in[6];
    const float* ln2_g  = (const float*)d_in[7];
    const float* ln2_b  = (const float*)d_in[8];
    const float* w_fc1  = (const float*)d_in[9];
    const float* b_fc1  = (const float*)d_in[10];
    const float* w_fc2  = (const float*)d_in[11];
    const float* b_fc2  = (const float*)d_in[12];
    const float* ls2_g  = (const float*)d_in[13];
    float* out = (float*)d_out;

    char* ws = (char*)d_ws;
    signed char* wqkv_s  = (signed char*)(ws + OFF_WQKV);
    signed char* wproj_s = (signed char*)(ws + OFF_WPROJ);
    signed char* wfc1_s  = (signed char*)(ws + OFF_WFC1);
    signed char* wfc2_s  = (signed char*)(ws + OFF_WFC2);
    float* a_proj  = (float*)(ws + OFF_APROJ);
    float* a_fc1   = (float*)(ws + OFF_AFC1);
    float* a_fc2   = (float*)(ws + OFF_AFC2);
    float* h2scale = (float*)(ws + OFF_H2SC);
    signed char* qk   = (signed char*)(ws + OFF_QK);
    signed char* vt   = (signed char*)(ws + OFF_VT);
    signed char* a1   = (signed char*)(ws + OFF_A1);
    signed char* a2   = (signed char*)(ws + OFF_A2);
    signed char* m1   = (signed char*)(ws + OFF_M1);
    signed char* h2   = (signed char*)(ws + OFF_H2);
    unsigned short* x1b  = (unsigned short*)(ws + OFF_X1B);
    unsigned short* xb16 = (unsigned short*)(ws + OFF_XB16);

    // front-end: wqkv sign + LN1+sign + bf16 copy of x (one dispatch)
    prep_front<<<2304 + NTOK, 256, 0, stream>>>(w_qkv, wqkv_s, x, ln1_g, ln1_b, a1, xb16);

    // QKV: sign(a1 @ wqkv^T); Q,K -> qk (pi-packed), V -> vt transposed
    gemm_i8<EPI_QKV><<<dim3(NQKV / 128, NTOK / 128), 256, 0, stream>>>(
        a1, wqkv_s, NQKV, CDIM, nullptr, nullptr, nullptr, qk, vt);

    // binary attention (exact i8) + wproj/wfc1/wfc2 prep on idle CUs
    attn_prep<<<5376, 256, 0, stream>>>(qk, vt, a2,
                                        w_proj, w_fc1, w_fc2,
                                        wproj_s, wfc1_s, wfc2_s,
                                        a_proj, a_fc1, a_fc2);

    // proj + layerscale residual: x1(bf16) = x + ls1*(ap*acc + bp)  (resid = xb16)
    gemm_resid<false><<<dim3(CDIM / 64, NTOK / 128), 256, 0, stream>>>(
        a2, wproj_s, CDIM, CDIM, a_proj, b_proj, ls1_g, xb16, 1.0f, nullptr, x1b);

    // LN2 (bf16 x1) + per-row i8 quant
    ln2q_kernel<<<NTOK, 256, 0, stream>>>(x1b, ln2_g, ln2_b, h2, h2scale);

    // fc1 + gelu -> fixed-scale i8 (pi-packed hidden layout)
    gemm_i8<EPI_GELU><<<dim3(HIDD / 128, NTOK / 128), 256, 0, stream>>>(
        h2, wfc1_s, HIDD, CDIM, a_fc1, b_fc1, h2scale, m1, nullptr);

    // fc2 + final residual: out(f32) = x1 + ls2*(af2*acc/16 + bf2)
    gemm_resid<true><<<dim3(CDIM / 64, NTOK / 128), 256, 0, stream>>>(
        m1, wfc2_s, CDIM, HIDD, a_fc2, b_fc2, ls2_g, x1b, 1.0f / MSCALE_INV, out, nullptr);
}

// Round 16
// 157.815 us; speedup vs baseline: 1.0069x; 1.0069x over previous
//
#include <hip/hip_runtime.h>

// ---- problem constants ----
#define NTOK 8192      // B*N = 8*1024
#define CDIM 768
#define HIDD 3072
#define NQKV 2304
#define SEQL 1024
#define NHEAD 12

typedef int i32x4 __attribute__((ext_vector_type(4)));
typedef float f32x4 __attribute__((ext_vector_type(4)));
typedef signed char sc16 __attribute__((ext_vector_type(16)));
typedef unsigned short us4 __attribute__((ext_vector_type(4)));

__device__ __forceinline__ unsigned short f32_to_bf16(float f) {
    unsigned int u = __float_as_uint(f);
    u += 0x7FFFu + ((u >> 16) & 1u);
    return (unsigned short)(u >> 16);
}
__device__ __forceinline__ float bf16_to_f32(unsigned short h) {
    return __uint_as_float(((unsigned)h) << 16);
}

// async global->LDS, 16B per lane. Dest must be wave-uniform base + lane*16.
__device__ __forceinline__ void gload_lds16(const void* g, void* l) {
    __builtin_amdgcn_global_load_lds(
        (const __attribute__((address_space(1))) unsigned int*)g,
        (__attribute__((address_space(3))) unsigned int*)l, 16, 0, 0);
}

// weight sign (+ optional alpha / pi-perm) helper
__device__ __forceinline__ void sign_alpha_row(
    const float* __restrict__ w, signed char* __restrict__ ws,
    float* __restrict__ alpha, int K, bool perm, int row, float* red)
{
    const float* wr = w + (size_t)row * K;
    signed char* wsr = ws + (size_t)row * K;
    float s = 0.f;
    for (int i = threadIdx.x; i < K; i += 256) {
        float v = wr[i];
        int ip = perm ? ((i & ~63) | (((i & 15) << 2) | ((i >> 4) & 3))) : i;
        wsr[ip] = (v >= 0.f) ? 1 : -1;
        s += fabsf(v);
    }
    if (alpha) {
        for (int off = 32; off > 0; off >>= 1) s += __shfl_down(s, off);
        if ((threadIdx.x & 63) == 0) red[threadIdx.x >> 6] = s;
        __syncthreads();
        if (threadIdx.x == 0) alpha[row] = (red[0] + red[1] + red[2] + red[3]) / (float)K;
    }
}

// ============================================================================
// Front-end: wqkv sign + LN1(+sign, packed u32) + bf16 copy of x (vectorized).
// Blocks: [0,2304) wqkv rows | [2304,10496) LN1 rows.
// ============================================================================
__global__ void __launch_bounds__(256) prep_front(
    const float* __restrict__ w_qkv, signed char* __restrict__ wqkv_s,
    const float* __restrict__ x, const float* __restrict__ ln1_g,
    const float* __restrict__ ln1_b, signed char* __restrict__ a1,
    unsigned short* __restrict__ xb16)
{
    const int blk = blockIdx.x;
    __shared__ float red[8];

    if (blk < 2304) {
        sign_alpha_row(w_qkv, wqkv_s, nullptr, CDIM, false, blk, red);
        return;
    }
    // ---- LN1 + sign (f32x4 loads, u32 packed stores), bf16 copy of x ----
    int row = blk - 2304;
    const int t = threadIdx.x;            // threads 0..191 active for data
    const bool act = t < 192;
    const float* xr = x + (size_t)row * CDIM;
    f32x4 xv = {0.f, 0.f, 0.f, 0.f};
    if (act) xv = *(const f32x4*)&xr[t * 4];
    if (act) {
        us4 h;
        h.x = f32_to_bf16(xv.x); h.y = f32_to_bf16(xv.y);
        h.z = f32_to_bf16(xv.z); h.w = f32_to_bf16(xv.w);
        *(us4*)&xb16[(size_t)row * CDIM + t * 4] = h;
    }
    float s = xv.x + xv.y + xv.z + xv.w;
    float s2 = xv.x * xv.x + xv.y * xv.y + xv.z * xv.z + xv.w * xv.w;
    for (int off = 32; off > 0; off >>= 1) { s += __shfl_down(s, off); s2 += __shfl_down(s2, off); }
    if ((t & 63) == 0) { red[t >> 6] = s; red[4 + (t >> 6)] = s2; }
    __syncthreads();
    float ts = red[0] + red[1] + red[2] + red[3];
    float t2 = red[4] + red[5] + red[6] + red[7];
    float mu = ts * (1.0f / CDIM);
    float var = t2 * (1.0f / CDIM) - mu * mu;
    float rstd = rsqrtf(var + 1e-5f);
    if (act) {
        f32x4 g4 = *(const f32x4*)&ln1_g[t * 4];
        f32x4 b4 = *(const f32x4*)&ln1_b[t * 4];
        unsigned pk = 0;
        float v[4] = {xv.x, xv.y, xv.z, xv.w};
        float gg[4] = {g4.x, g4.y, g4.z, g4.w};
        float bb[4] = {b4.x, b4.y, b4.z, b4.w};
#pragma unroll
        for (int e = 0; e < 4; e++) {
            float val = (v[e] - mu) * rstd * gg[e] + bb[e];
            pk |= (unsigned)(unsigned char)(signed char)((val >= 0.f) ? 1 : -1) << (8 * e);
        }
        *(unsigned*)(a1 + (size_t)row * CDIM + t * 4) = pk;
    }
}

// LayerNorm (bf16 x1, vectorized us4) -> per-row i8 quant (packed u32)
__global__ void __launch_bounds__(256) ln2q_kernel(const unsigned short* __restrict__ x, const float* __restrict__ g,
                                                   const float* __restrict__ b, signed char* __restrict__ out,
                                                   float* __restrict__ rowscale) {
    int row = blockIdx.x;
    const int t = threadIdx.x;
    const bool act = t < 192;
    float v[4] = {0.f, 0.f, 0.f, 0.f};
    if (act) {
        us4 xv = *(const us4*)&x[(size_t)row * CDIM + t * 4];
        v[0] = bf16_to_f32(xv.x); v[1] = bf16_to_f32(xv.y);
        v[2] = bf16_to_f32(xv.z); v[3] = bf16_to_f32(xv.w);
    }
    float s = v[0] + v[1] + v[2] + v[3];
    float s2 = v[0] * v[0] + v[1] * v[1] + v[2] * v[2] + v[3] * v[3];
    for (int off = 32; off > 0; off >>= 1) { s += __shfl_down(s, off); s2 += __shfl_down(s2, off); }
    __shared__ float red[8];
    __shared__ float redm[4];
    if ((t & 63) == 0) { red[t >> 6] = s; red[4 + (t >> 6)] = s2; }
    __syncthreads();
    float ts = red[0] + red[1] + red[2] + red[3];
    float t2 = red[4] + red[5] + red[6] + red[7];
    float mu = ts * (1.0f / CDIM);
    float var = t2 * (1.0f / CDIM) - mu * mu;
    float rstd = rsqrtf(var + 1e-5f);
    float a[4] = {0.f, 0.f, 0.f, 0.f};
    float mx = 0.f;
    if (act) {
        f32x4 g4 = *(const f32x4*)&g[t * 4];
        f32x4 b4 = *(const f32x4*)&b[t * 4];
        float gg[4] = {g4.x, g4.y, g4.z, g4.w};
        float bb[4] = {b4.x, b4.y, b4.z, b4.w};
#pragma unroll
        for (int e = 0; e < 4; e++) {
            a[e] = (v[e] - mu) * rstd * gg[e] + bb[e];
            mx = fmaxf(mx, fabsf(a[e]));
        }
    }
    for (int off = 32; off > 0; off >>= 1) mx = fmaxf(mx, __shfl_down(mx, off));
    if ((t & 63) == 0) redm[t >> 6] = mx;
    __syncthreads();
    float rmax = fmaxf(fmaxf(redm[0], redm[1]), fmaxf(redm[2], redm[3]));
    rmax = fmaxf(rmax, 1e-20f);
    float inv = 127.f / rmax;
    if (act) {
        unsigned pk = 0;
#pragma unroll
        for (int e = 0; e < 4; e++)
            pk |= (unsigned)(unsigned char)(signed char)__float2int_rn(a[e] * inv) << (8 * e);
        *(unsigned*)(out + (size_t)row * CDIM + t * 4) = pk;
    }
    if (t == 0) rowscale[row] = rmax * (1.f / 127.f);
}

// ---------- i8 GEMM 256x128, 8 waves (4m x 2n): QKV / GELU epilogues ----------
enum { EPI_GELU = 2, EPI_QKV = 3 };
#define MSCALE_INV 16.0f

template<int EPI>
__global__ void __launch_bounds__(512, 4) gemm_i8(
    const signed char* __restrict__ A, const signed char* __restrict__ B,
    int M, int N, int K,
    const float* __restrict__ alpha, const float* __restrict__ bias,
    const float* __restrict__ rowscale,
    signed char* __restrict__ outB, signed char* __restrict__ vtB)
{
    __shared__ __align__(16) char lds_raw[3 * (256 + 128) * 64];   // 72 KB -> 2 blocks/CU
    auto As = (signed char (*)[256][64])lds_raw;
    auto Bs = (signed char (*)[128][64])(lds_raw + 3 * 256 * 64);

    const int tid = threadIdx.x, ln = tid & 63, w = tid >> 6;
    const int wm = w >> 1, wn = w & 1;                 // 4m x 2n waves
    const int lq = ln & 15, khi = ln >> 4;

    const int nwg = gridDim.x * gridDim.y;
    const int id = blockIdx.y * gridDim.x + blockIdx.x;
    const int nid = (id & 7) * (nwg >> 3) + (id >> 3);
    const int bxs = nid % gridDim.x, bys = nid / gridDim.x;
    const int bm = bys * 256, bn = bxs * 128;

    const i32x4 iz = {0, 0, 0, 0};
    i32x4 acc[4][4];
#pragma unroll
    for (int m = 0; m < 4; m++)
#pragma unroll
        for (int n = 0; n < 4; n++) acc[m][n] = iz;

    const int srow = tid >> 2, scol = (tid & 3) * 16;
    const int ssrc = ((tid & 3) ^ ((srow >> 1) & 3)) * 16;
    const int sa = 16 * (khi ^ ((lq >> 1) & 3));

    auto STAGE = [&](int p, int k0) {
        gload_lds16(A + (size_t)(bm + srow) * K + k0 + ssrc, &As[p][srow][scol]);
        gload_lds16(A + (size_t)(bm + 128 + srow) * K + k0 + ssrc, &As[p][128 + srow][scol]);
        gload_lds16(B + (size_t)(bn + srow) * K + k0 + ssrc, &Bs[p][srow][scol]);
    };
    auto COMPUTE = [&](int p, bool prefetch, int knext) {
        i32x4 aF[4], bF[4];
#pragma unroll
        for (int m = 0; m < 4; m++) aF[m] = *(const i32x4*)&As[p][wm * 64 + m * 16 + lq][sa];
#pragma unroll
        for (int n = 0; n < 4; n++) bF[n] = *(const i32x4*)&Bs[p][wn * 64 + n * 16 + lq][sa];
        if (prefetch) STAGE((p + 2) % 3, knext);
        __builtin_amdgcn_s_setprio(1);
#pragma unroll
        for (int m = 0; m < 4; m++)
#pragma unroll
            for (int n = 0; n < 4; n++)
                acc[m][n] = __builtin_amdgcn_mfma_i32_16x16x64_i8(aF[m], bF[n], acc[m][n], 0, 0, 0);
        __builtin_amdgcn_s_setprio(0);
    };

    const int nst = K >> 6;            // 12
    STAGE(0, 0);
    STAGE(1, 64);
#pragma unroll 1
    for (int t = 0; t < nst - 1; t++) {
        asm volatile("s_waitcnt vmcnt(3)" ::: "memory");
        asm volatile("s_waitcnt lgkmcnt(0)" ::: "memory");
        __builtin_amdgcn_s_barrier();
        COMPUTE(t % 3, t + 2 < nst, (t + 2) << 6);
    }
    asm volatile("s_waitcnt vmcnt(0)" ::: "memory");
    asm volatile("s_waitcnt lgkmcnt(0)" ::: "memory");
    __builtin_amdgcn_s_barrier();
    COMPUTE((nst - 1) % 3, false, 0);

    const int r0 = bm + wm * 64;
    const int c0 = bn + wn * 64;       // wave's 64-col group

    if constexpr (EPI == EPI_GELU) {
        float al[4], bi[4];
#pragma unroll
        for (int n = 0; n < 4; n++) {
            al[n] = alpha[c0 + n * 16 + lq];
            bi[n] = bias[c0 + n * 16 + lq];
        }
#pragma unroll
        for (int m = 0; m < 4; m++)
#pragma unroll
            for (int i = 0; i < 4; i++) {
                int r = r0 + m * 16 + khi * 4 + i;
                float rs = rowscale[r];
                unsigned pk = 0;
#pragma unroll
                for (int n = 0; n < 4; n++) {
                    float t = al[n] * ((float)acc[m][n][i] * rs) + bi[n];
                    float y2 = 1.5957691f * t + 0.07135481f * t * t * t;
                    float ge = t * __builtin_amdgcn_rcpf(1.0f + __expf(-y2));
                    float qf = fminf(fmaxf(ge * MSCALE_INV, -127.f), 127.f);
                    pk |= (unsigned)(unsigned char)(signed char)__float2int_rn(qf) << (8 * n);
                }
                *(unsigned*)(outB + (size_t)r * N + c0 + lq * 4) = pk;
            }
    } else {  // EPI_QKV
        if (c0 < 1536) {
#pragma unroll
            for (int m = 0; m < 4; m++)
#pragma unroll
                for (int i = 0; i < 4; i++) {
                    int r = r0 + m * 16 + khi * 4 + i;
                    unsigned pk = 0;
#pragma unroll
                    for (int n = 0; n < 4; n++)
                        pk |= (unsigned)(unsigned char)(signed char)((acc[m][n][i] >= 0) ? 1 : -1) << (8 * n);
                    *(unsigned*)(outB + (size_t)r * 1536 + c0 + lq * 4) = pk;
                }
        } else {
#pragma unroll
            for (int m = 0; m < 4; m++)
#pragma unroll
                for (int n = 0; n < 4; n++) {
                    int cg = c0 + n * 16 + lq - 1536;
                    int hh = cg >> 6, dd = cg & 63;
                    int rb = r0 + m * 16 + khi * 4;
                    unsigned pk = 0;
#pragma unroll
                    for (int i = 0; i < 4; i++)
                        pk |= (unsigned)(unsigned char)(signed char)((acc[m][n][i] >= 0) ? 1 : -1) << (8 * i);
                    *(unsigned*)(vtB + (((size_t)(rb >> 10) * NHEAD + hh) * 64 + dd) * SEQL + (rb & 1023)) = pk;
                }
        }
    }
}

// ---------- 128x64 RESID GEMM (proj / fc2) ----------
// 3-buffer counted-vmcnt pipeline + T14 preloaded epilogue operands.
// resid is always bf16. OUTF32=false (proj): output x1 bf16; true (fc2): f32.
template<bool OUTF32>
__global__ void __launch_bounds__(256) gemm_resid(
    const signed char* __restrict__ A, const signed char* __restrict__ B,
    int N, int K,
    const float* __restrict__ alpha, const float* __restrict__ bias,
    const float* __restrict__ ls, const unsigned short* __restrict__ residH,
    float ascale,
    float* __restrict__ outF, unsigned short* __restrict__ outH)
{
    __shared__ __align__(16) char lds_raw[3 * (128 + 64) * 64];   // 36 KB; epi Cf 128x68 f32 fits
    auto As = (signed char (*)[128][64])lds_raw;
    auto Bs = (signed char (*)[64][64])(lds_raw + 3 * 128 * 64);

    const int tid = threadIdx.x, ln = tid & 63, w = tid >> 6;
    const int wm = w >> 1, wn = w & 1;
    const int lq = ln & 15, khi = ln >> 4;

    const int nwg = gridDim.x * gridDim.y;
    const int id = blockIdx.y * gridDim.x + blockIdx.x;
    const int nid = (id & 7) * (nwg >> 3) + (id >> 3);
    const int bxs = nid % gridDim.x, bys = nid / gridDim.x;
    const int bm = bys * 128, bn = bxs * 64;

    // ---- T14 preload: epilogue operands issued before any staging ----
    const int erow = tid >> 4;           // 0..15
    const int ec4 = (tid & 15) * 4;
    f32x4 a4 = *(const f32x4*)&alpha[bn + ec4];
    f32x4 b4 = *(const f32x4*)&bias[bn + ec4];
    f32x4 l4 = *(const f32x4*)&ls[bn + ec4];
    us4 rH[8];
#pragma unroll
    for (int p = 0; p < 8; p++) {
        size_t g = (size_t)(bm + p * 16 + erow) * N + bn + ec4;
        rH[p] = *(const us4*)&residH[g];
    }

    const i32x4 iz = {0, 0, 0, 0};
    i32x4 acc[4][2];
#pragma unroll
    for (int m = 0; m < 4; m++)
#pragma unroll
        for (int n = 0; n < 2; n++) acc[m][n] = iz;

    const int srow = tid >> 2, scol = (tid & 3) * 16;
    const int ssrc = ((tid & 3) ^ ((srow >> 1) & 3)) * 16;
    const int sa = 16 * (khi ^ ((lq >> 1) & 3));

    auto STAGE = [&](int p, int k0) {
        gload_lds16(A + (size_t)(bm + srow) * K + k0 + ssrc, &As[p][srow][scol]);
        gload_lds16(A + (size_t)(bm + 64 + srow) * K + k0 + ssrc, &As[p][64 + srow][scol]);
        gload_lds16(B + (size_t)(bn + srow) * K + k0 + ssrc, &Bs[p][srow][scol]);
    };
    auto COMPUTE = [&](int p, bool prefetch, int knext) {
        i32x4 aF[4], bF[2];
#pragma unroll
        for (int m = 0; m < 4; m++) aF[m] = *(const i32x4*)&As[p][wm * 64 + m * 16 + lq][sa];
#pragma unroll
        for (int n = 0; n < 2; n++) bF[n] = *(const i32x4*)&Bs[p][wn * 32 + n * 16 + lq][sa];
        if (prefetch) STAGE((p + 2) % 3, knext);
        __builtin_amdgcn_s_setprio(1);
#pragma unroll
        for (int m = 0; m < 4; m++)
#pragma unroll
            for (int n = 0; n < 2; n++)
                acc[m][n] = __builtin_amdgcn_mfma_i32_16x16x64_i8(aF[m], bF[n], acc[m][n], 0, 0, 0);
        __builtin_amdgcn_s_setprio(0);
    };

    const int nst = K >> 6;            // 12 or 48
    STAGE(0, 0);
    STAGE(1, 64);
#pragma unroll 1
    for (int t = 0; t < nst - 1; t++) {
        asm volatile("s_waitcnt vmcnt(3)" ::: "memory");   // stage t done (preloads retire first)
        asm volatile("s_waitcnt lgkmcnt(0)" ::: "memory");
        __builtin_amdgcn_s_barrier();
        COMPUTE(t % 3, t + 2 < nst, (t + 2) << 6);
    }
    asm volatile("s_waitcnt vmcnt(0)" ::: "memory");
    asm volatile("s_waitcnt lgkmcnt(0)" ::: "memory");
    __builtin_amdgcn_s_barrier();
    COMPUTE((nst - 1) % 3, false, 0);

    // ---- epilogue: LDS transpose -> pure FMA + coalesced store (resid in regs) ----
    __syncthreads();
    float (*Cf)[68] = (float (*)[68])lds_raw;
#pragma unroll
    for (int m = 0; m < 4; m++)
#pragma unroll
        for (int n = 0; n < 2; n++)
#pragma unroll
            for (int i = 0; i < 4; i++)
                Cf[wm * 64 + m * 16 + khi * 4 + i][wn * 32 + n * 16 + lq] =
                    (float)acc[m][n][i] * ascale;
    __syncthreads();
#pragma unroll
    for (int p = 0; p < 8; p++) {
        int row = p * 16 + erow;
        f32x4 v4 = *(const f32x4*)&Cf[row][ec4];
        size_t g = (size_t)(bm + row) * N + bn + ec4;
        f32x4 r;
        r.x = bf16_to_f32(rH[p].x); r.y = bf16_to_f32(rH[p].y);
        r.z = bf16_to_f32(rH[p].z); r.w = bf16_to_f32(rH[p].w);
        f32x4 o4 = r + l4 * (a4 * v4 + b4);
        if constexpr (OUTF32) {
            *(f32x4*)&outF[g] = o4;
        } else {
            us4 h;
            h.x = f32_to_bf16(o4.x); h.y = f32_to_bf16(o4.y);
            h.z = f32_to_bf16(o4.z); h.w = f32_to_bf16(o4.w);
            *(us4*)&outH[g] = h;
        }
    }
}

// ---------- binary attention (exact i8) + fused wproj/wfc1/wfc2 prep ----------
__global__ void __launch_bounds__(256) attn_prep(
    const signed char* __restrict__ qk, const signed char* __restrict__ vt,
    signed char* __restrict__ a2,
    const float* __restrict__ w_proj, const float* __restrict__ w_fc1,
    const float* __restrict__ w_fc2,
    signed char* __restrict__ wproj_s, signed char* __restrict__ wfc1_s,
    signed char* __restrict__ wfc2_s,
    float* __restrict__ a_proj, float* __restrict__ a_fc1, float* __restrict__ a_fc2)
{
    const int blk = blockIdx.x;
    if (blk >= 768) {
        __shared__ float red[4];
        if (blk < 1536)      sign_alpha_row(w_proj, wproj_s, a_proj, CDIM, true,  blk - 768, red);
        else if (blk < 4608) sign_alpha_row(w_fc1,  wfc1_s,  a_fc1,  CDIM, false, blk - 1536, red);
        else                 sign_alpha_row(w_fc2,  wfc2_s,  a_fc2,  HIDD, true,  blk - 4608, red);
        return;
    }

    const int id = blk;                              // 0..767
    const int nid = (id & 7) * 96 + (id >> 3);
    const int bh = nid >> 3, qb = nid & 7;
    const int b = bh / NHEAD, h = bh % NHEAD;
    const int tid = threadIdx.x, ln = tid & 63, w = tid >> 6;
    const int lq = ln & 15, khi = ln >> 4;

    __shared__ signed char Ks[64][80];
    __shared__ signed char Vts[64][80];
    __shared__ signed char Pw[4][32][80];

    const size_t tokbase = (size_t)b * SEQL;
    const int q0 = qb * 128 + w * 32;
    const int str = tid >> 2, stc = (tid & 3) * 16;
    const size_t vtrow = ((size_t)bh * 64 + str) * SEQL;

    i32x4 qfrag[2];
#pragma unroll
    for (int qf = 0; qf < 2; qf++)
        qfrag[qf] = *(const i32x4*)(qk + (tokbase + q0 + qf * 16 + lq) * 1536 + h * 64 + khi * 16);

    const i32x4 iz = {0, 0, 0, 0};
    i32x4 o[2][4];
#pragma unroll
    for (int qf = 0; qf < 2; qf++)
#pragma unroll
        for (int df = 0; df < 4; df++) o[qf][df] = iz;

    auto LOADJ = [&](int j, sc16& kr, sc16& vr) {
        kr = *(const sc16*)(qk + (tokbase + j * 64 + str) * 1536 + 768 + h * 64 + stc);
        vr = *(const sc16*)(vt + vtrow + j * 64 + stc);
    };
    auto STORE = [&](const sc16& kr, const sc16& vr) {
        *(sc16*)&Ks[str][stc] = kr;
        *(sc16*)&Vts[str][stc] = vr;
    };
    auto COMPUTE = [&]() {
        i32x4 kfrag[4];
#pragma unroll
        for (int kf = 0; kf < 4; kf++)
            kfrag[kf] = *(const i32x4*)&Ks[kf * 16 + lq][khi * 16];
#pragma unroll
        for (int kf = 0; kf < 4; kf++) {
#pragma unroll
            for (int qf = 0; qf < 2; qf++) {
                i32x4 st = __builtin_amdgcn_mfma_i32_16x16x64_i8(kfrag[kf], qfrag[qf], iz, 0, 0, 0);
                unsigned pb = (st[0] > 0 ? 1u : 0u) | (st[1] > 0 ? 0x100u : 0u) |
                              (st[2] > 0 ? 0x10000u : 0u) | (st[3] > 0 ? 0x1000000u : 0u);
                *(unsigned*)&Pw[w][qf * 16 + lq][kf * 16 + khi * 4] = pb;
            }
        }
        i32x4 pa[2];
#pragma unroll
        for (int qf = 0; qf < 2; qf++)
            pa[qf] = *(const i32x4*)&Pw[w][qf * 16 + lq][khi * 16];
#pragma unroll
        for (int df = 0; df < 4; df++) {
            i32x4 vfr = *(const i32x4*)&Vts[df * 16 + lq][khi * 16];
#pragma unroll
            for (int qf = 0; qf < 2; qf++)
                o[qf][df] = __builtin_amdgcn_mfma_i32_16x16x64_i8(pa[qf], vfr, o[qf][df], 0, 0, 0);
        }
    };

    sc16 ka, va, kb, vb;
    LOADJ(0, ka, va);
#pragma unroll 1
    for (int jj = 0; jj < 16; jj += 2) {
        __syncthreads();
        STORE(ka, va);
        __syncthreads();
        LOADJ(jj + 1, kb, vb);
        COMPUTE();
        __syncthreads();
        STORE(kb, vb);
        __syncthreads();
        if (jj + 2 < 16) LOADJ(jj + 2, ka, va);
        COMPUTE();
    }

    // epilogue: pi-packed u32: a2[token][h*64 + lq*4 + df] = sign(O[.][df*16+lq])
#pragma unroll
    for (int qf = 0; qf < 2; qf++)
#pragma unroll
        for (int i = 0; i < 4; i++) {
            int qrow = q0 + qf * 16 + khi * 4 + i;
            unsigned pk = 0;
#pragma unroll
            for (int df = 0; df < 4; df++)
                pk |= (unsigned)(unsigned char)(signed char)((o[qf][df][i] >= 0) ? 1 : -1) << (8 * df);
            *(unsigned*)(a2 + (tokbase + qrow) * CDIM + h * 64 + lq * 4) = pk;
        }
}

// ---------- workspace layout (bytes) ----------
static const size_t OFF_WQKV  = 0;          // 2304*768   = 1769472
static const size_t OFF_WPROJ = 1769472;    // 768*768    = 589824
static const size_t OFF_WFC1  = 2359296;    // 3072*768   = 2359296
static const size_t OFF_WFC2  = 4718592;    // 768*3072   = 2359296
static const size_t OFF_APROJ = 7077888;    // 768*4
static const size_t OFF_AFC1  = 7080960;    // 3072*4
static const size_t OFF_AFC2  = 7093248;    // 768*4
static const size_t OFF_H2SC  = 7096320;    // 8192*4
static const size_t OFF_QK    = 7129088;    // 8192*1536  = 12582912 (dead after attn)
static const size_t OFF_VT    = 19712000;   // 96*64*1024 = 6291456  (dead after attn)
static const size_t OFF_A1    = 26003456;   // 8192*768   = 6291456
static const size_t OFF_A2    = 32294912;   // 8192*768   = 6291456
static const size_t OFF_M1    = 38586368;   // 8192*3072  = 25165824
static const size_t OFF_H2    = 63752192;   // 8192*768   = 6291456
static const size_t OFF_X1B   = OFF_QK;     // bf16 x1 aliases qk
static const size_t OFF_XB16  = OFF_M1;     // bf16 x aliases m1 (dead until fc1)
// total = 70043648 bytes

extern "C" void kernel_launch(void* const* d_in, const int* in_sizes, int n_in,
                              void* d_out, int out_size, void* d_ws, size_t ws_size,
                              hipStream_t stream) {
    const float* x      = (const float*)d_in[0];
    const float* ln1_g  = (const float*)d_in[1];
    const float* ln1_b  = (const float*)d_in[2];
    const float* w_qkv  = (const float*)d_in[3];
    const float* w_proj = (const float*)d_in[4];
    const float* b_proj = (const float*)d_in[5];
    const float* ls1_g  = (const float*)d_in[6];
    const float* ln2_g  = (const float*)d_in[7];
    const float* ln2_b  = (const float*)d_in[8];
    const float* w_fc1  = (const float*)d_in[9];
    const float* b_fc1  = (const float*)d_in[10];
    const float* w_fc2  = (const float*)d_in[11];
    const float* b_fc2  = (const float*)d_in[12];
    const float* ls2_g  = (const float*)d_in[13];
    float* out = (float*)d_out;

    char* ws = (char*)d_ws;
    signed char* wqkv_s  = (signed char*)(ws + OFF_WQKV);
    signed char* wproj_s = (signed char*)(ws + OFF_WPROJ);
    signed char* wfc1_s  = (signed char*)(ws + OFF_WFC1);
    signed char* wfc2_s  = (signed char*)(ws + OFF_WFC2);
    float* a_proj  = (float*)(ws + OFF_APROJ);
    float* a_fc1   = (float*)(ws + OFF_AFC1);
    float* a_fc2   = (float*)(ws + OFF_AFC2);
    float* h2scale = (float*)(ws + OFF_H2SC);
    signed char* qk   = (signed char*)(ws + OFF_QK);
    signed char* vt   = (signed char*)(ws + OFF_VT);
    signed char* a1   = (signed char*)(ws + OFF_A1);
    signed char* a2   = (signed char*)(ws + OFF_A2);
    signed char* m1   = (signed char*)(ws + OFF_M1);
    signed char* h2   = (signed char*)(ws + OFF_H2);
    unsigned short* x1b  = (unsigned short*)(ws + OFF_X1B);
    unsigned short* xb16 = (unsigned short*)(ws + OFF_XB16);

    // front-end: wqkv sign + LN1+sign + bf16 copy of x (one dispatch)
    prep_front<<<2304 + NTOK, 256, 0, stream>>>(w_qkv, wqkv_s, x, ln1_g, ln1_b, a1, xb16);

    // QKV: sign(a1 @ wqkv^T); Q,K -> qk (pi-packed), V -> vt transposed
    gemm_i8<EPI_QKV><<<dim3(NQKV / 128, NTOK / 256), 512, 0, stream>>>(
        a1, wqkv_s, NTOK, NQKV, CDIM, nullptr, nullptr, nullptr, qk, vt);

    // binary attention (exact i8) + wproj/wfc1/wfc2 prep on idle CUs
    attn_prep<<<5376, 256, 0, stream>>>(qk, vt, a2,
                                        w_proj, w_fc1, w_fc2,
                                        wproj_s, wfc1_s, wfc2_s,
                                        a_proj, a_fc1, a_fc2);

    // proj + layerscale residual: x1(bf16) = x + ls1*(ap*acc + bp)  (resid = xb16)
    gemm_resid<false><<<dim3(CDIM / 64, NTOK / 128), 256, 0, stream>>>(
        a2, wproj_s, CDIM, CDIM, a_proj, b_proj, ls1_g, xb16, 1.0f, nullptr, x1b);

    // LN2 (bf16 x1) + per-row i8 quant
    ln2q_kernel<<<NTOK, 256, 0, stream>>>(x1b, ln2_g, ln2_b, h2, h2scale);

    // fc1 + gelu -> fixed-scale i8 (pi-packed hidden layout)
    gemm_i8<EPI_GELU><<<dim3(HIDD / 128, NTOK / 256), 512, 0, stream>>>(
        h2, wfc1_s, NTOK, HIDD, CDIM, a_fc1, b_fc1, h2scale, m1, nullptr);

    // fc2 + final residual: out(f32) = x1 + ls2*(af2*acc/16 + bf2)
    gemm_resid<true><<<dim3(CDIM / 64, NTOK / 128), 256, 0, stream>>>(
        m1, wfc2_s, CDIM, HIDD, a_fc2, b_fc2, ls2_g, x1b, 1.0f / MSCALE_INV, out, nullptr);
}